// Round 19
// baseline (253.202 us; speedup 1.0000x reference)
//
#include <hip/hip_runtime.h>
#include <math.h>

#define BB 64
#define TT 128
#define HH 16
#define GG 64      // 4*H
#define IN0_ 65
#define VV 32000
#define NROWS (BB*TT)   // 8192
#define RSTRIDE 68      // insh row stride (floats), 16B-aligned

typedef float f32x4 __attribute__((ext_vector_type(4)));

__device__ __forceinline__ float bcast(float v, int lane) {
    return __uint_as_float(__builtin_amdgcn_readlane(__float_as_uint(v), lane));
}
__device__ __forceinline__ float fastrcp(float x) {
    return __builtin_amdgcn_rcpf(x);
}
// tanh(x) = 1 - 2/(e^(2x)+1), via v_exp + v_rcp (no fp32 div chain)
__device__ __forceinline__ float tanhc(float x) {
    return 1.0f - 2.0f * fastrcp(__expf(2.0f * x) + 1.0f);
}

// ---------------- Kernel A: fused front, 4-steps/barrier + balanced waves ----------
// 64 blocks x 256 threads. Phase 2: wave0 = layer0 chain only, publishes h0(t) to
// LDS (16 floats/step); wave1 = layer1 chain, computes the Wih1·h0 dot itself from
// the published h0 (4x broadcast ds_read_b128 per step). Barriers 64 -> 32.
// h0sh double-buffered on super-step parity (wave0 rewrites a parity only after
// the barrier that wave1 passes having finished reading it).
__global__ __launch_bounds__(256) void fused_front(const float* __restrict__ x,
                           const float* __restrict__ emb,
                           const float* __restrict__ Wih0, const float* __restrict__ bih0,
                           const float* __restrict__ bhh0,
                           const float* __restrict__ h0in, const float* __restrict__ c0in,
                           const float* __restrict__ Whh0,
                           const float* __restrict__ Wih1, const float* __restrict__ Whh1,
                           const float* __restrict__ bih1, const float* __restrict__ bhh1,
                           float* __restrict__ y1, float* __restrict__ outTail) {
    __shared__ float insh[TT * RSTRIDE];   // 34816 B: inp rows -> xp rows (in-place)
    __shared__ float wsh[GG * IN0_];       // 16640 B: Wih0 staged
    __shared__ float h0sh[2][4][HH];       // 512 B: [parity][sub-step][h-index]
    const int b   = blockIdx.x;
    const int tid = threadIdx.x;           // 0..255
    const int wave = tid >> 6, g = tid & 63;
    const float* xb = x + (size_t)b * TT * 9;

    // stage Wih0 (coalesced float4)
    for (int i = tid; i < GG * IN0_ / 4; i += 256) {
        float4 wv = *reinterpret_cast<const float4*>(Wih0 + i * 4);
        wsh[i*4+0] = wv.x; wsh[i*4+1] = wv.y; wsh[i*4+2] = wv.z; wsh[i*4+3] = wv.w;
    }
    // gather embeddings
    #pragma unroll
    for (int it = 0; it < 8; ++it) {
        int q = tid + it * 256;            // 0..2047
        int p = q >> 1, half = q & 1;
        int r = p >> 3, f = p & 7;
        int idx = (int)xb[r * 9 + f];
        const float* er = emb + (size_t)idx * 8 + half * 4;
        float4 e = *reinterpret_cast<const float4*>(er);
        float* d = &insh[r * RSTRIDE + f * 8 + half * 4];
        d[0] = e.x; d[1] = e.y; d[2] = e.z; d[3] = e.w;
    }
    if (tid < TT) insh[tid * RSTRIDE + 64] = xb[tid * 9 + 8];
    __syncthreads();

    // phase 1: wave w -> rows [w*32, w*32+32)
    {
        float wreg[IN0_];
        #pragma unroll
        for (int k = 0; k < IN0_; ++k) wreg[k] = wsh[g * IN0_ + k];
        const float bias0 = bih0[g] + bhh0[g];
        for (int r = 0; r < 32; ++r) {
            const int row = wave * 32 + r;
            const float* ir = &insh[row * RSTRIDE];
            float a0 = bias0, a1 = 0.0f, a2 = 0.0f, a3 = 0.0f;
            #pragma unroll
            for (int k4 = 0; k4 < 16; ++k4) {
                f32x4 v = *reinterpret_cast<const f32x4*>(ir + k4 * 4);
                float p0 = v.x * wreg[k4*4+0] + v.y * wreg[k4*4+1]
                         + v.z * wreg[k4*4+2] + v.w * wreg[k4*4+3];
                if ((k4 & 3) == 0) a0 += p0;
                else if ((k4 & 3) == 1) a1 += p0;
                else if ((k4 & 3) == 2) a2 += p0;
                else a3 += p0;
            }
            float acc = (a0 + a1) + (a2 + a3) + ir[64] * wreg[64];
            insh[row * RSTRIDE + g] = acc;
        }
    }
    __syncthreads();

    const int j = g & 15;
    const int type = g >> 4;                       // 0=i, 1=f, 2=g(tanh), 3=o
    const float mconst = (type == 2) ? 2.0f : 1.0f;
    const float sconst = (type == 2) ? 2.0f : 1.0f;

    // wave0: wa = Whh0 row; wave1: wa = Whh1 row, wb = Wih1 row
    float wa[HH], wb[HH];
    #pragma unroll
    for (int k = 0; k < HH; ++k) {
        wa[k] = (wave == 0) ? Whh0[g * HH + k] : Whh1[g * HH + k];
        wb[k] = (wave == 1) ? Wih1[g * HH + k] : 0.0f;
    }
    const float bias1 = bih1[g] + bhh1[g];

    float hv = (wave == 0) ? h0in[b * HH + j] : h0in[BB * HH + b * HH + j];
    float cv = (wave == 0) ? c0in[b * HH + j] : c0in[BB * HH + b * HH + j];

    for (int s = 0; s < TT / 4; ++s) {
        if (wave == 0) {
            #pragma unroll
            for (int u = 0; u < 4; ++u) {
                const int t = 4 * s + u;
                float a0 = insh[t * RSTRIDE + g], a1 = 0.0f, a2 = 0.0f, a3 = 0.0f;
                #pragma unroll
                for (int k = 0; k < 4; ++k) {
                    a0 += bcast(hv, k)      * wa[k];
                    a1 += bcast(hv, k + 4)  * wa[k + 4];
                    a2 += bcast(hv, k + 8)  * wa[k + 8];
                    a3 += bcast(hv, k + 12) * wa[k + 12];
                }
                float acc = (a0 + a1) + (a2 + a3);
                float tv = 1.0f - mconst * fastrcp(__expf(sconst * acc) + 1.0f);
                float ti = __shfl(tv, j);
                float tf = __shfl(tv, j + 16);
                float tg = __shfl(tv, j + 32);
                float to = __shfl(tv, j + 48);
                cv = tf * cv + ti * tg;
                hv = to * tanhc(cv);
                if (g < HH) h0sh[s & 1][u][g] = hv;   // publish h0(t)
            }
        }
        __syncthreads();
        if (wave == 1) {
            #pragma unroll
            for (int u = 0; u < 4; ++u) {
                const int t = 4 * s + u;
                // z1 = Wih1 · h0(t), h0 via broadcast vector LDS reads
                const f32x4* hp = reinterpret_cast<const f32x4*>(&h0sh[s & 1][u][0]);
                f32x4 ha = hp[0], hb = hp[1], hc = hp[2], hd = hp[3];
                float a0 = bias1, a1 = 0.0f, a2 = 0.0f, a3 = 0.0f;
                a0 += ha.x * wb[0]  + ha.y * wb[1]  + ha.z * wb[2]  + ha.w * wb[3];
                a1 += hb.x * wb[4]  + hb.y * wb[5]  + hb.z * wb[6]  + hb.w * wb[7];
                a2 += hc.x * wb[8]  + hc.y * wb[9]  + hc.z * wb[10] + hc.w * wb[11];
                a3 += hd.x * wb[12] + hd.y * wb[13] + hd.z * wb[14] + hd.w * wb[15];
                #pragma unroll
                for (int k = 0; k < 4; ++k) {
                    a0 += bcast(hv, k)      * wa[k];
                    a1 += bcast(hv, k + 4)  * wa[k + 4];
                    a2 += bcast(hv, k + 8)  * wa[k + 8];
                    a3 += bcast(hv, k + 12) * wa[k + 12];
                }
                float acc = (a0 + a1) + (a2 + a3);
                float tv = 1.0f - mconst * fastrcp(__expf(sconst * acc) + 1.0f);
                float ti = __shfl(tv, j);
                float tf = __shfl(tv, j + 16);
                float tg = __shfl(tv, j + 32);
                float to = __shfl(tv, j + 48);
                cv = tf * cv + ti * tg;
                hv = to * tanhc(cv);
                if (g < HH) y1[(size_t)(b * TT + t) * HH + g] = hv;
            }
        }
    }

    if (g < HH) {
        if (wave == 0) {
            outTail[b * HH + g]               = hv;   // h0T
            outTail[2 * BB * HH + b * HH + g] = cv;   // c0T
        } else if (wave == 1) {
            outTail[BB * HH + b * HH + g]     = hv;   // h1T
            outTail[3 * BB * HH + b * HH + g] = cv;   // c1T
        }
    }
}

// ---------------- Kernel B: FC head — byte-identical to round 7 --------------------
__global__ __launch_bounds__(256) void fc_kernel(const float* __restrict__ y1,
                          const float* __restrict__ fcw, const float* __restrict__ fcb,
                          float* __restrict__ out) {
    const int tid  = threadIdx.x;
    const int v0   = blockIdx.x * 1024 + tid * 4;   // column slice (fast grid dim)
    const int row0 = blockIdx.y * 32;               // row band

    if (v0 >= VV) return;

    float w[4][HH];
    #pragma unroll
    for (int jj = 0; jj < 4; ++jj) {
        const float4* wp = reinterpret_cast<const float4*>(fcw + (size_t)(v0 + jj) * HH);
        float4 a = wp[0], b = wp[1], c = wp[2], d = wp[3];
        w[jj][0]=a.x; w[jj][1]=a.y; w[jj][2]=a.z; w[jj][3]=a.w;
        w[jj][4]=b.x; w[jj][5]=b.y; w[jj][6]=b.z; w[jj][7]=b.w;
        w[jj][8]=c.x; w[jj][9]=c.y; w[jj][10]=c.z; w[jj][11]=c.w;
        w[jj][12]=d.x; w[jj][13]=d.y; w[jj][14]=d.z; w[jj][15]=d.w;
    }
    const float4 bias = *reinterpret_cast<const float4*>(fcb + v0);

    const f32x4* yrow = reinterpret_cast<const f32x4*>(y1 + (size_t)row0 * HH);

    float* orow = out + (size_t)row0 * VV + v0;
    #pragma unroll 4
    for (int r = 0; r < 32; ++r) {
        f32x4 y0 = yrow[r * 4 + 0];
        f32x4 y1v = yrow[r * 4 + 1];
        f32x4 y2 = yrow[r * 4 + 2];
        f32x4 y3 = yrow[r * 4 + 3];
        float a0 = bias.x, a1 = bias.y, a2 = bias.z, a3 = bias.w;
        #pragma unroll
        for (int jj = 0; jj < 4; ++jj) {
            float* wj = w[jj];
            float acc = y0.x*wj[0] + y0.y*wj[1] + y0.z*wj[2] + y0.w*wj[3]
                      + y1v.x*wj[4] + y1v.y*wj[5] + y1v.z*wj[6] + y1v.w*wj[7]
                      + y2.x*wj[8] + y2.y*wj[9] + y2.z*wj[10] + y2.w*wj[11]
                      + y3.x*wj[12] + y3.y*wj[13] + y3.z*wj[14] + y3.w*wj[15];
            if (jj == 0) a0 += acc;
            else if (jj == 1) a1 += acc;
            else if (jj == 2) a2 += acc;
            else a3 += acc;
        }
        f32x4 o;
        o.x = a0; o.y = a1; o.z = a2; o.w = a3;
        __builtin_nontemporal_store(o, reinterpret_cast<f32x4*>(orow));
        orow += VV;
    }
}

extern "C" void kernel_launch(void* const* d_in, const int* in_sizes, int n_in,
                              void* d_out, int out_size, void* d_ws, size_t ws_size,
                              hipStream_t stream) {
    const float* x    = (const float*)d_in[0];
    const float* h0   = (const float*)d_in[1];
    const float* c0   = (const float*)d_in[2];
    const float* emb  = (const float*)d_in[3];
    const float* Wih0 = (const float*)d_in[4];
    const float* Whh0 = (const float*)d_in[5];
    const float* bih0 = (const float*)d_in[6];
    const float* bhh0 = (const float*)d_in[7];
    const float* Wih1 = (const float*)d_in[8];
    const float* Whh1 = (const float*)d_in[9];
    const float* bih1 = (const float*)d_in[10];
    const float* bhh1 = (const float*)d_in[11];
    const float* fcw  = (const float*)d_in[12];
    const float* fcb  = (const float*)d_in[13];

    float* out = (float*)d_out;
    float* y1  = (float*)d_ws;                     // NROWS*16 floats
    float* outTail = out + (size_t)NROWS * VV;     // hN then cN

    fused_front<<<BB, 256, 0, stream>>>(x, emb, Wih0, bih0, bhh0, h0, c0,
                                        Whh0, Wih1, Whh1, bih1, bhh1, y1, outTail);
    fc_kernel<<<dim3(32, NROWS / 32), 256, 0, stream>>>(y1, fcw, fcb, out);
}

// Round 20
// 248.133 us; speedup vs baseline: 1.0204x; 1.0204x over previous
//
#include <hip/hip_runtime.h>
#include <math.h>

#define BB 64
#define TT 128
#define HH 16
#define GG 64      // 4*H
#define IN0_ 65
#define VV 32000
#define NROWS (BB*TT)   // 8192
#define RSTRIDE 68      // insh row stride (floats), 16B-aligned

typedef float f32x4 __attribute__((ext_vector_type(4)));

__device__ __forceinline__ float bcast(float v, int lane) {
    return __uint_as_float(__builtin_amdgcn_readlane(__float_as_uint(v), lane));
}
__device__ __forceinline__ float fastrcp(float x) {
    return __builtin_amdgcn_rcpf(x);
}
// tanh(x) = 1 - 2/(e^(2x)+1), via v_exp + v_rcp (no fp32 div chain)
__device__ __forceinline__ float tanhc(float x) {
    return 1.0f - 2.0f * fastrcp(__expf(2.0f * x) + 1.0f);
}

// ---------------- Kernel A: fused front, 2-steps-per-barrier recurrence -----------
// (byte-identical to round 18 — best measured configuration, 248.7 us)
__global__ __launch_bounds__(256) void fused_front(const float* __restrict__ x,
                           const float* __restrict__ emb,
                           const float* __restrict__ Wih0, const float* __restrict__ bih0,
                           const float* __restrict__ bhh0,
                           const float* __restrict__ h0in, const float* __restrict__ c0in,
                           const float* __restrict__ Whh0,
                           const float* __restrict__ Wih1, const float* __restrict__ Whh1,
                           const float* __restrict__ bih1, const float* __restrict__ bhh1,
                           float* __restrict__ y1, float* __restrict__ outTail) {
    __shared__ float insh[TT * RSTRIDE];   // 34816 B: inp rows -> xp rows (in-place)
    __shared__ float wsh[GG * IN0_];       // 16640 B: Wih0 staged
    __shared__ float z1buf[2][2][GG];      // 1 KB: [super-step parity][sub-step][gate]
    const int b   = blockIdx.x;
    const int tid = threadIdx.x;           // 0..255
    const int wave = tid >> 6, g = tid & 63;
    const float* xb = x + (size_t)b * TT * 9;

    // stage Wih0 (coalesced float4)
    for (int i = tid; i < GG * IN0_ / 4; i += 256) {
        float4 wv = *reinterpret_cast<const float4*>(Wih0 + i * 4);
        wsh[i*4+0] = wv.x; wsh[i*4+1] = wv.y; wsh[i*4+2] = wv.z; wsh[i*4+3] = wv.w;
    }
    // gather embeddings
    #pragma unroll
    for (int it = 0; it < 8; ++it) {
        int q = tid + it * 256;            // 0..2047
        int p = q >> 1, half = q & 1;
        int r = p >> 3, f = p & 7;
        int idx = (int)xb[r * 9 + f];
        const float* er = emb + (size_t)idx * 8 + half * 4;
        float4 e = *reinterpret_cast<const float4*>(er);
        float* d = &insh[r * RSTRIDE + f * 8 + half * 4];
        d[0] = e.x; d[1] = e.y; d[2] = e.z; d[3] = e.w;
    }
    if (tid < TT) insh[tid * RSTRIDE + 64] = xb[tid * 9 + 8];
    __syncthreads();

    // phase 1: wave w -> rows [w*32, w*32+32)
    {
        float wreg[IN0_];
        #pragma unroll
        for (int k = 0; k < IN0_; ++k) wreg[k] = wsh[g * IN0_ + k];
        const float bias0 = bih0[g] + bhh0[g];
        for (int r = 0; r < 32; ++r) {
            const int row = wave * 32 + r;
            const float* ir = &insh[row * RSTRIDE];
            float a0 = bias0, a1 = 0.0f, a2 = 0.0f, a3 = 0.0f;
            #pragma unroll
            for (int k4 = 0; k4 < 16; ++k4) {
                f32x4 v = *reinterpret_cast<const f32x4*>(ir + k4 * 4);
                float p0 = v.x * wreg[k4*4+0] + v.y * wreg[k4*4+1]
                         + v.z * wreg[k4*4+2] + v.w * wreg[k4*4+3];
                if ((k4 & 3) == 0) a0 += p0;
                else if ((k4 & 3) == 1) a1 += p0;
                else if ((k4 & 3) == 2) a2 += p0;
                else a3 += p0;
            }
            float acc = (a0 + a1) + (a2 + a3) + ir[64] * wreg[64];
            insh[row * RSTRIDE + g] = acc;
        }
    }
    __syncthreads();

    const int j = g & 15;
    const int type = g >> 4;                       // 0=i, 1=f, 2=g(tanh), 3=o
    const float mconst = (type == 2) ? 2.0f : 1.0f;
    const float sconst = (type == 2) ? 2.0f : 1.0f;

    float wa[HH], wb[HH];   // wave0: wa=Whh0 row, wb=Wih1 row; wave1: wa=Whh1 row
    #pragma unroll
    for (int k = 0; k < HH; ++k) {
        wa[k] = (wave == 0) ? Whh0[g * HH + k] : Whh1[g * HH + k];
        wb[k] = (wave == 0) ? Wih1[g * HH + k] : 0.0f;
    }
    const float bias1 = bih1[g] + bhh1[g];

    float hv = (wave == 0) ? h0in[b * HH + j] : h0in[BB * HH + b * HH + j];
    float cv = (wave == 0) ? c0in[b * HH + j] : c0in[BB * HH + b * HH + j];

    for (int s = 0; s < TT / 2; ++s) {
        if (wave == 0) {
            #pragma unroll
            for (int u = 0; u < 2; ++u) {
                const int t = 2 * s + u;
                float a0 = insh[t * RSTRIDE + g], a1 = 0.0f, a2 = 0.0f, a3 = 0.0f;
                #pragma unroll
                for (int k = 0; k < 4; ++k) {
                    a0 += bcast(hv, k)      * wa[k];
                    a1 += bcast(hv, k + 4)  * wa[k + 4];
                    a2 += bcast(hv, k + 8)  * wa[k + 8];
                    a3 += bcast(hv, k + 12) * wa[k + 12];
                }
                float acc = (a0 + a1) + (a2 + a3);
                float tv = 1.0f - mconst * fastrcp(__expf(sconst * acc) + 1.0f);
                float ti = __shfl(tv, j);
                float tf = __shfl(tv, j + 16);
                float tg = __shfl(tv, j + 32);
                float to = __shfl(tv, j + 48);
                cv = tf * cv + ti * tg;
                hv = to * tanhc(cv);
                float za = 0.0f, zb = 0.0f;
                #pragma unroll
                for (int k = 0; k < 8; ++k) {
                    za += bcast(hv, k)     * wb[k];
                    zb += bcast(hv, k + 8) * wb[k + 8];
                }
                z1buf[s & 1][u][g] = za + zb;
            }
        }
        __syncthreads();
        if (wave == 1) {
            #pragma unroll
            for (int u = 0; u < 2; ++u) {
                const int t = 2 * s + u;
                float a0 = bias1 + z1buf[s & 1][u][g], a1 = 0.0f, a2 = 0.0f, a3 = 0.0f;
                #pragma unroll
                for (int k = 0; k < 4; ++k) {
                    a0 += bcast(hv, k)      * wa[k];
                    a1 += bcast(hv, k + 4)  * wa[k + 4];
                    a2 += bcast(hv, k + 8)  * wa[k + 8];
                    a3 += bcast(hv, k + 12) * wa[k + 12];
                }
                float acc = (a0 + a1) + (a2 + a3);
                float tv = 1.0f - mconst * fastrcp(__expf(sconst * acc) + 1.0f);
                float ti = __shfl(tv, j);
                float tf = __shfl(tv, j + 16);
                float tg = __shfl(tv, j + 32);
                float to = __shfl(tv, j + 48);
                cv = tf * cv + ti * tg;
                hv = to * tanhc(cv);
                if (g < HH) y1[(size_t)(b * TT + t) * HH + g] = hv;
            }
        }
    }

    if (g < HH) {
        if (wave == 0) {
            outTail[b * HH + g]               = hv;   // h0T
            outTail[2 * BB * HH + b * HH + g] = cv;   // c0T
        } else if (wave == 1) {
            outTail[BB * HH + b * HH + g]     = hv;   // h1T
            outTail[3 * BB * HH + b * HH + g] = cv;   // c1T
        }
    }
}

// ---------------- Kernel B: FC head — byte-identical to round 7 --------------------
__global__ __launch_bounds__(256) void fc_kernel(const float* __restrict__ y1,
                          const float* __restrict__ fcw, const float* __restrict__ fcb,
                          float* __restrict__ out) {
    const int tid  = threadIdx.x;
    const int v0   = blockIdx.x * 1024 + tid * 4;   // column slice (fast grid dim)
    const int row0 = blockIdx.y * 32;               // row band

    if (v0 >= VV) return;

    float w[4][HH];
    #pragma unroll
    for (int jj = 0; jj < 4; ++jj) {
        const float4* wp = reinterpret_cast<const float4*>(fcw + (size_t)(v0 + jj) * HH);
        float4 a = wp[0], b = wp[1], c = wp[2], d = wp[3];
        w[jj][0]=a.x; w[jj][1]=a.y; w[jj][2]=a.z; w[jj][3]=a.w;
        w[jj][4]=b.x; w[jj][5]=b.y; w[jj][6]=b.z; w[jj][7]=b.w;
        w[jj][8]=c.x; w[jj][9]=c.y; w[jj][10]=c.z; w[jj][11]=c.w;
        w[jj][12]=d.x; w[jj][13]=d.y; w[jj][14]=d.z; w[jj][15]=d.w;
    }
    const float4 bias = *reinterpret_cast<const float4*>(fcb + v0);

    const f32x4* yrow = reinterpret_cast<const f32x4*>(y1 + (size_t)row0 * HH);

    float* orow = out + (size_t)row0 * VV + v0;
    #pragma unroll 4
    for (int r = 0; r < 32; ++r) {
        f32x4 y0 = yrow[r * 4 + 0];
        f32x4 y1v = yrow[r * 4 + 1];
        f32x4 y2 = yrow[r * 4 + 2];
        f32x4 y3 = yrow[r * 4 + 3];
        float a0 = bias.x, a1 = bias.y, a2 = bias.z, a3 = bias.w;
        #pragma unroll
        for (int jj = 0; jj < 4; ++jj) {
            float* wj = w[jj];
            float acc = y0.x*wj[0] + y0.y*wj[1] + y0.z*wj[2] + y0.w*wj[3]
                      + y1v.x*wj[4] + y1v.y*wj[5] + y1v.z*wj[6] + y1v.w*wj[7]
                      + y2.x*wj[8] + y2.y*wj[9] + y2.z*wj[10] + y2.w*wj[11]
                      + y3.x*wj[12] + y3.y*wj[13] + y3.z*wj[14] + y3.w*wj[15];
            if (jj == 0) a0 += acc;
            else if (jj == 1) a1 += acc;
            else if (jj == 2) a2 += acc;
            else a3 += acc;
        }
        f32x4 o;
        o.x = a0; o.y = a1; o.z = a2; o.w = a3;
        __builtin_nontemporal_store(o, reinterpret_cast<f32x4*>(orow));
        orow += VV;
    }
}

extern "C" void kernel_launch(void* const* d_in, const int* in_sizes, int n_in,
                              void* d_out, int out_size, void* d_ws, size_t ws_size,
                              hipStream_t stream) {
    const float* x    = (const float*)d_in[0];
    const float* h0   = (const float*)d_in[1];
    const float* c0   = (const float*)d_in[2];
    const float* emb  = (const float*)d_in[3];
    const float* Wih0 = (const float*)d_in[4];
    const float* Whh0 = (const float*)d_in[5];
    const float* bih0 = (const float*)d_in[6];
    const float* bhh0 = (const float*)d_in[7];
    const float* Wih1 = (const float*)d_in[8];
    const float* Whh1 = (const float*)d_in[9];
    const float* bih1 = (const float*)d_in[10];
    const float* bhh1 = (const float*)d_in[11];
    const float* fcw  = (const float*)d_in[12];
    const float* fcb  = (const float*)d_in[13];

    float* out = (float*)d_out;
    float* y1  = (float*)d_ws;                     // NROWS*16 floats
    float* outTail = out + (size_t)NROWS * VV;     // hN then cN

    fused_front<<<BB, 256, 0, stream>>>(x, emb, Wih0, bih0, bhh0, h0, c0,
                                        Whh0, Wih1, Whh1, bih1, bhh1, y1, outTail);
    fc_kernel<<<dim3(32, NROWS / 32), 256, 0, stream>>>(y1, fcw, fcb, out);
}